// Round 6
// baseline (4299.266 us; speedup 1.0000x reference)
//
// R6: resubmit of R4/R5 crash-fix (broker timeouts; never executed). Experiment in flight:
// does 377MB->249MB ws reduction fix R3's SIGABRT? Layout: a3/a1 share A13, oh aliases x,
// t3/zt3 live in dead pinv ping-pong bufs; ws guard; all stream ops are kernels.
// Footprint: 62,329,920 floats = 237.8 MiB. Numerics identical to audited baseline.
#include <hip/hip_runtime.h>

#define TB 256

constexpr int BATCH = 2;
constexpr int NF    = 6000;
constexpr int NTOK  = 6085;   // 1 cls + 6084
constexpr int NPIX  = 6084;   // 78*78
constexpr int HS    = 78;
constexpr int NP    = 6144;   // padded seq for landmarks
constexpr int PAD   = 59;     // front zero-pad
constexpr int CD    = 512;
constexpr int NH    = 8;
constexpr int DH    = 64;
constexpr int LMM   = 256;
constexpr int LSEG  = 24;     // NP / LMM
constexpr int D3    = 1536;
constexpr float SCALE = 0.125f;
constexpr int RESK  = 33;

// ---------------- workspace layout (floats) ----------------
constexpr long SZ_H   = (long)BATCH*NTOK*CD;     // 6,231,040
constexpr long SZ_X   = (long)BATCH*NP*CD;       // 6,291,456 (== SZ_OH, oh aliases x)
constexpr long SZ_QKV = (long)BATCH*NP*D3;       // 18,874,368
constexpr long SZ_L   = (long)BATCH*NH*LMM*DH;   // 262,144
constexpr long SZ_A13 = (long)BATCH*NH*NP*LMM;   // 25,165,824 (a3 then a1 then tr)
constexpr long SZ_A2  = (long)BATCH*NH*LMM*LMM;  // 1,048,576
constexpr long SZ_P   = SZ_A2;                   // pinv ping-pong buffer

constexpr long O_H   = 0;
constexpr long O_X   = O_H   + SZ_H;             // also OH
constexpr long O_QKV = O_X   + SZ_X;
constexpr long O_QL  = O_QKV + SZ_QKV;
constexpr long O_KL  = O_QL  + SZ_L;
constexpr long O_A13 = O_KL  + SZ_L;
constexpr long O_A2  = O_A13 + SZ_A13;
constexpr long O_P0  = O_A2  + SZ_A2;
constexpr long O_P1  = O_P0  + SZ_P;
constexpr long O_P2  = O_P1  + SZ_P;
constexpr long O_P3  = O_P2  + SZ_P;
constexpr long O_SCAL= O_P3  + SZ_P;
constexpr long WS_FLOATS = O_SCAL + 64;
// 62,329,920 floats = 237.8 MiB

// ---------------- reductions (blockDim == 256) ----------------
__device__ __forceinline__ float blkSum(float v, float* red) {
  #pragma unroll
  for (int o = 32; o > 0; o >>= 1) v += __shfl_xor(v, o);
  if ((threadIdx.x & 63) == 0) red[threadIdx.x >> 6] = v;
  __syncthreads();
  v = red[0] + red[1] + red[2] + red[3];
  __syncthreads();
  return v;
}
__device__ __forceinline__ float blkMax(float v, float* red) {
  #pragma unroll
  for (int o = 32; o > 0; o >>= 1) v = fmaxf(v, __shfl_xor(v, o));
  if ((threadIdx.x & 63) == 0) red[threadIdx.x >> 6] = v;
  __syncthreads();
  v = fmaxf(fmaxf(red[0], red[1]), fmaxf(red[2], red[3]));
  __syncthreads();
  return v;
}

// ---------------- generic tiled GEMM ----------------
// C[bh] = A[bh] @ B[bh]; BT: B given as (N x K) row-major (multiply by B^T)
// EP: 0 none | 1 c0*I - P | 2 c0*P | 3 P + bias[col] | 4 atomicAdd
template<int BT, int EP>
__global__ __launch_bounds__(256)
void gemm_k(const float* __restrict__ A, const float* __restrict__ Bp, float* __restrict__ Cp,
            int Ksz,
            long sAb, long sAh, int lda,
            long sBb, long sBh, int ldb,
            long sCb, long sCh, int ldc,
            int splitk, float c0, const float* __restrict__ bias, int Hdiv)
{
  constexpr int BM = 64, BN = 64, BK = 16;
  int z = blockIdx.z;
  int split = z % splitk;
  int bh = z / splitk;
  int bb = bh / Hdiv, hh = bh % Hdiv;
  const float* Ab = A  + bb*sAb + hh*sAh;
  const float* Bb = Bp + bb*sBb + hh*sBh;
  float*       Cb = Cp + bb*sCb + hh*sCh;
  int n0 = blockIdx.x * BN;
  int m0 = blockIdx.y * BM;
  int kPer = Ksz / splitk;
  int k0beg = split * kPer, k0end = k0beg + kPer;

  __shared__ float As[BK][BM + 4];
  __shared__ float Bs[BK][BN + 4];

  int tid = threadIdx.x;
  int tx = tid & 15, ty = tid >> 4;
  float acc[4][4] = {};

  for (int k0 = k0beg; k0 < k0end; k0 += BK) {
    {
      int m  = tid >> 2;
      int kk = (tid & 3) << 2;
      float4 v = *reinterpret_cast<const float4*>(Ab + (long)(m0 + m)*lda + k0 + kk);
      As[kk+0][m] = v.x; As[kk+1][m] = v.y; As[kk+2][m] = v.z; As[kk+3][m] = v.w;
    }
    if (BT == 0) {
      int kk = tid >> 4;
      int n4 = (tid & 15) << 2;
      float4 v = *reinterpret_cast<const float4*>(Bb + (long)(k0 + kk)*ldb + n0 + n4);
      *reinterpret_cast<float4*>(&Bs[kk][n4]) = v;
    } else {
      int n  = tid >> 2;
      int kk = (tid & 3) << 2;
      float4 v = *reinterpret_cast<const float4*>(Bb + (long)(n0 + n)*ldb + k0 + kk);
      Bs[kk+0][n] = v.x; Bs[kk+1][n] = v.y; Bs[kk+2][n] = v.z; Bs[kk+3][n] = v.w;
    }
    __syncthreads();
    #pragma unroll
    for (int kk = 0; kk < BK; ++kk) {
      float4 av = *reinterpret_cast<const float4*>(&As[kk][ty << 2]);
      float4 bv = *reinterpret_cast<const float4*>(&Bs[kk][tx << 2]);
      float a[4] = {av.x, av.y, av.z, av.w};
      float b[4] = {bv.x, bv.y, bv.z, bv.w};
      #pragma unroll
      for (int i = 0; i < 4; ++i)
        #pragma unroll
        for (int j = 0; j < 4; ++j)
          acc[i][j] += a[i] * b[j];
    }
    __syncthreads();
  }

  #pragma unroll
  for (int i = 0; i < 4; ++i) {
    int gm = m0 + (ty << 2) + i;
    long rowOff = (long)gm*ldc + n0 + (tx << 2);
    if (EP == 4) {
      #pragma unroll
      for (int j = 0; j < 4; ++j) atomicAdd(&Cb[rowOff + j], acc[i][j]);
    } else {
      float4 vv;
      float* pv = reinterpret_cast<float*>(&vv);
      #pragma unroll
      for (int j = 0; j < 4; ++j) {
        int gn = n0 + (tx << 2) + j;
        float r = acc[i][j];
        if (EP == 1) r = (gm == gn ? c0 : 0.f) - r;
        else if (EP == 2) r = c0 * r;
        else if (EP == 3) r = r + bias[gn];
        pv[j] = r;
      }
      *reinterpret_cast<float4*>(&Cb[rowOff]) = vv;
    }
  }
}

static void gemm(hipStream_t s, int BT, int EP,
                 const float* A, const float* Bp, float* Cp,
                 int Msz, int Nsz, int Ksz,
                 long sAb, long sAh, int lda,
                 long sBb, long sBh, int ldb,
                 long sCb, long sCh, int ldc,
                 int batch, int Hdiv, int splitk, float c0, const float* bias)
{
  dim3 g(Nsz/64, Msz/64, batch*splitk), t(256);
  #define GCALL(bt,ep) gemm_k<bt,ep><<<g,t,0,s>>>(A,Bp,Cp,Ksz,sAb,sAh,lda,sBb,sBh,ldb,sCb,sCh,ldc,splitk,c0,bias,Hdiv)
  if (BT == 0) {
    switch (EP) {
      case 0: GCALL(0,0); break; case 1: GCALL(0,1); break; case 2: GCALL(0,2); break;
      case 3: GCALL(0,3); break; case 4: GCALL(0,4); break;
    }
  } else {
    switch (EP) { case 0: GCALL(1,0); break; case 2: GCALL(1,2); break; }
  }
  #undef GCALL
}

// ---------------- misc kernels ----------------
__global__ __launch_bounds__(TB) void zero_k(float* __restrict__ p, long n) {
  long i = (long)blockIdx.x*TB + threadIdx.x;
  if (i < n) p[i] = 0.f;
}

__global__ __launch_bounds__(TB) void build_h_k(const float* __restrict__ f,
                                                const float* __restrict__ cls,
                                                float* __restrict__ h) {
  int r = blockIdx.x; int b = r / NTOK; int n = r % NTOK;
  const float* src;
  if (n == 0) src = cls;
  else { int rr = n - 1; if (rr >= NF) rr -= NF; src = f + ((long)b*NF + rr)*CD; }
  int t = threadIdx.x;
  h[(long)r*CD + t]       = src[t];
  h[(long)r*CD + t + 256] = src[t + 256];
}

__global__ __launch_bounds__(TB) void ln_pad_k(const float* __restrict__ h,
                                               const float* __restrict__ g,
                                               const float* __restrict__ be,
                                               float* __restrict__ x) {
  __shared__ float red[4];
  int r = blockIdx.x; int b = r / NP; int p = r % NP;
  float* o = x + (long)r*CD;
  int t = threadIdx.x;
  if (p < PAD) { o[t] = 0.f; o[t + 256] = 0.f; return; }
  const float* row = h + ((long)b*NTOK + (p - PAD))*CD;
  float v1 = row[t], v2 = row[t + 256];
  float mu = blkSum(v1 + v2, red) * (1.f/CD);
  float d1 = v1 - mu, d2 = v2 - mu;
  float var = blkSum(d1*d1 + d2*d2, red) * (1.f/CD);
  float inv = rsqrtf(var + 1e-5f);
  o[t]       = d1*inv*g[t]       + be[t];
  o[t + 256] = d2*inv*g[t + 256] + be[t + 256];
}

__global__ __launch_bounds__(TB) void ln_out_k(const float* __restrict__ h,
                                               const float* __restrict__ g,
                                               const float* __restrict__ be,
                                               float* __restrict__ out) {
  __shared__ float red[4];
  int r = blockIdx.x;
  const float* row = h + (long)r*CD;
  int t = threadIdx.x;
  float v1 = row[t], v2 = row[t + 256];
  float mu = blkSum(v1 + v2, red) * (1.f/CD);
  float d1 = v1 - mu, d2 = v2 - mu;
  float var = blkSum(d1*d1 + d2*d2, red) * (1.f/CD);
  float inv = rsqrtf(var + 1e-5f);
  out[(long)r*CD + t]       = d1*inv*g[t]       + be[t];
  out[(long)r*CD + t + 256] = d2*inv*g[t + 256] + be[t + 256];
}

__global__ __launch_bounds__(64) void landmark_k(const float* __restrict__ qkv,
                                                 float* __restrict__ ql,
                                                 float* __restrict__ kl) {
  int bid = blockIdx.x; int j = bid % LMM; int bh = bid / LMM;
  int b = bh / NH, h = bh % NH;
  int d = threadIdx.x;
  const float* qb = qkv + (long)b*NP*D3 + (long)j*LSEG*D3 + h*64 + d;
  float sq = 0.f, sk = 0.f;
  #pragma unroll 4
  for (int l = 0; l < LSEG; ++l) { sq += qb[(long)l*D3]; sk += qb[(long)l*D3 + CD]; }
  ql[((long)bh*LMM + j)*DH + d] = sq * (SCALE / LSEG);
  kl[((long)bh*LMM + j)*DH + d] = sk * (1.0f / LSEG);
}

__global__ __launch_bounds__(TB) void softmax256_k(float* __restrict__ a) {
  __shared__ float red[4];
  long row = blockIdx.x;
  float* p = a + row*256;
  float v = p[threadIdx.x];
  float m = blkMax(v, red);
  float e = __expf(v - m);
  float s = blkSum(e, red);
  p[threadIdx.x] = e / s;
}

__global__ __launch_bounds__(TB) void softmax_np_k(float* __restrict__ a) {
  __shared__ float buf[NP];
  __shared__ float red[4];
  long row = blockIdx.x;
  float* p = a + row*(long)NP;
  int t = threadIdx.x;
  float m = -1e30f;
  #pragma unroll
  for (int c = 0; c < NP/TB; ++c) { float v = p[c*TB + t]; buf[c*TB + t] = v; m = fmaxf(m, v); }
  m = blkMax(m, red);
  float s = 0.f;
  #pragma unroll
  for (int c = 0; c < NP/TB; ++c) { float e = __expf(buf[c*TB + t] - m); buf[c*TB + t] = e; s += e; }
  s = blkSum(s, red);
  float inv = 1.f / s;
  #pragma unroll
  for (int c = 0; c < NP/TB; ++c) p[c*TB + t] = buf[c*TB + t] * inv;
}

__global__ void scal_init_k(float* scal) { if (threadIdx.x < 8) scal[threadIdx.x] = 0.f; }

__global__ __launch_bounds__(TB) void pinv_prep_k(const float* __restrict__ a2, float* scal) {
  __shared__ float red[4];
  int bh = blockIdx.x;
  const float* X = a2 + (long)bh*LMM*LMM;
  int t = threadIdx.x;
  float cs = 0.f, rs = 0.f;
  for (int i = 0; i < LMM; ++i) cs += X[(long)i*LMM + t];
  for (int j = 0; j < LMM; ++j) rs += X[(long)t*LMM + j];
  float mc = blkMax(cs, red);
  float mr = blkMax(rs, red);
  if (t == 0) {
    atomicMax((unsigned int*)&scal[0], __float_as_uint(mr));
    atomicMax((unsigned int*)&scal[1], __float_as_uint(mc));
  }
}

__global__ __launch_bounds__(TB) void z0_k(const float* __restrict__ a2,
                                           const float* __restrict__ scal,
                                           float* __restrict__ z) {
  int i = blockIdx.x; int bh = blockIdx.y; int j = threadIdx.x;
  float inv = 1.f / (scal[0] * scal[1]);
  z[((long)bh*LMM + i)*LMM + j] = a2[((long)bh*LMM + j)*LMM + i] * inv;
}

__global__ __launch_bounds__(TB) void t7_k(const float* __restrict__ xz, float* __restrict__ t1) {
  int i = blockIdx.x; int bh = blockIdx.y; int j = threadIdx.x;
  long off = ((long)bh*LMM + i)*LMM + j;
  t1[off] = (i == j ? 7.f : 0.f) - xz[off];
}

__global__ __launch_bounds__(TB) void addres_k(const float* __restrict__ qkv,
                                               const float* __restrict__ rw,
                                               float* __restrict__ oh) {
  int bid = blockIdx.x;
  int i4 = bid % (NP/4); int bh = bid / (NP/4);
  int b = bh / NH, h = bh % NH;
  int i = i4*4 + (threadIdx.x >> 6);
  int d = threadIdx.x & 63;
  const float* vb = qkv + (long)b*NP*D3 + 2*CD + h*64 + d;
  float s = 0.f;
  #pragma unroll
  for (int t = 0; t < RESK; ++t) {
    int j = i + t - RESK/2;
    if (j >= 0 && j < NP) s += rw[h*RESK + t] * vb[(long)j*D3];
  }
  oh[((long)bh*NP + i)*DH + d] += s;
}

__global__ __launch_bounds__(TB) void tr_k(const float* __restrict__ oh, float* __restrict__ tr) {
  int r = blockIdx.x; int b = r / NP; int i = r % NP;
  #pragma unroll
  for (int cc = 0; cc < 2; ++cc) {
    int c = threadIdx.x + cc*256;
    int hh = c >> 6, d = c & 63;
    tr[(long)r*CD + c] = oh[(((long)b*NH + hh)*NP + i)*DH + d];
  }
}

__global__ __launch_bounds__(TB) void addh_k(const float* __restrict__ ao, float* __restrict__ h) {
  long idx = (long)blockIdx.x*TB + threadIdx.x;
  long b = idx / ((long)NTOK*CD);
  long rem = idx - b*(long)NTOK*CD;
  h[idx] += ao[b*(long)NP*CD + (long)PAD*CD + rem];
}

__global__ __launch_bounds__(TB) void ppeg_k(const float* __restrict__ h,
                                             const float* __restrict__ w7, const float* __restrict__ b7,
                                             const float* __restrict__ w5, const float* __restrict__ b5,
                                             const float* __restrict__ w3, const float* __restrict__ b3,
                                             float* __restrict__ tmp) {
  int bid = blockIdx.x;
  int b = bid / NPIX, n = bid % NPIX;
  int y = n / HS, x = n % HS;
  const float* hb = h + (long)b*NTOK*CD + CD;  // row 1 = pixel 0
  #pragma unroll
  for (int cc = 0; cc < 2; ++cc) {
    int c = threadIdx.x + cc*256;
    float acc = hb[(long)n*CD + c] + b7[c] + b5[c] + b3[c];
    for (int dy = 0; dy < 7; ++dy) {
      int yy = y + dy - 3; if (yy < 0 || yy >= HS) continue;
      for (int dx = 0; dx < 7; ++dx) {
        int xx = x + dx - 3; if (xx < 0 || xx >= HS) continue;
        float w = w7[(long)c*49 + dy*7 + dx];
        if (dy >= 1 && dy <= 5 && dx >= 1 && dx <= 5) w += w5[(long)c*25 + (dy-1)*5 + (dx-1)];
        if (dy >= 2 && dy <= 4 && dx >= 2 && dx <= 4) w += w3[(long)c*9  + (dy-2)*3 + (dx-2)];
        acc += w * hb[((long)yy*HS + xx)*CD + c];
      }
    }
    tmp[(long)bid*CD + c] = acc;
  }
}

__global__ __launch_bounds__(TB) void ppeg_copy_k(const float* __restrict__ tmp, float* __restrict__ h) {
  int r = blockIdx.x; int b = r / NPIX; int n = r % NPIX;
  int t = threadIdx.x;
  float* dst = h + ((long)b*NTOK + 1 + n)*CD;
  const float* s = tmp + (long)r*CD;
  dst[t] = s[t]; dst[t + 256] = s[t + 256];
}

// ---------------- attention block ----------------
static void attention(float* ws, hipStream_t s,
                      const float* ln_g, const float* ln_b,
                      const float* qkv_w, const float* out_w, const float* out_b,
                      const float* res_w)
{
  float* h   = ws + O_H;
  float* x   = ws + O_X;     // ln output; later reused as oh and as out-proj dest
  float* qkv = ws + O_QKV;
  float* ql  = ws + O_QL;  float* kl = ws + O_KL;
  float* a13 = ws + O_A13;   // a3, then a1, then tr staging
  float* a2  = ws + O_A2;
  float* scal= ws + O_SCAL;
  float* bufs[4] = {ws + O_P0, ws + O_P1, ws + O_P2, ws + O_P3};

  const long sP = (long)LMM*LMM;
  const long sL = (long)LMM*DH;

  ln_pad_k<<<BATCH*NP, TB, 0, s>>>(h, ln_g, ln_b, x);
  gemm(s, 0, 0, x, qkv_w, qkv, BATCH*NP, D3, CD,
       0, 0, CD,  0, 0, D3,  0, 0, D3,  1, 1, 1, 0.f, nullptr);
  landmark_k<<<BATCH*NH*LMM, 64, 0, s>>>(qkv, ql, kl);

  // ---- attn3 = softmax(ql @ k^T) into a13 (first use) ----
  float* a3 = a13;
  gemm(s, 1, 0, ql, qkv + CD, a3, LMM, NP, DH,
       (long)NH*sL, sL, DH,  (long)NP*D3, 64, D3,  (long)NH*LMM*NP, (long)LMM*NP, NP,
       BATCH*NH, NH, 1, 0.f, nullptr);
  softmax_np_k<<<BATCH*NH*LMM, TB, 0, s>>>(a3);

  // ---- attn2 = softmax(ql @ kl^T) ----
  gemm(s, 1, 0, ql, kl, a2, LMM, LMM, DH,
       (long)NH*sL, sL, DH,  (long)NH*sL, sL, DH,  (long)NH*sP, sP, LMM,
       BATCH*NH, NH, 1, 0.f, nullptr);
  softmax256_k<<<BATCH*NH*LMM, TB, 0, s>>>(a2);

  // ---- pinv(attn2) ----
  scal_init_k<<<1, 64, 0, s>>>(scal);
  pinv_prep_k<<<BATCH*NH, TB, 0, s>>>(a2, scal);
  int zi = 0;
  z0_k<<<dim3(LMM, BATCH*NH), TB, 0, s>>>(a2, scal, bufs[zi]);
  for (int it = 0; it < 6; ++it) {
    int oi[3], c = 0;
    for (int i = 0; i < 4; ++i) if (i != zi) oi[c++] = i;
    float* Z  = bufs[zi];
    float* XZ = bufs[oi[0]]; float* T1 = bufs[oi[1]]; float* T2 = bufs[oi[2]];
    gemm(s, 0, 0, a2, Z, XZ, LMM, LMM, LMM,
         (long)NH*sP, sP, LMM, (long)NH*sP, sP, LMM, (long)NH*sP, sP, LMM,
         BATCH*NH, NH, 1, 0.f, nullptr);
    t7_k<<<dim3(LMM, BATCH*NH), TB, 0, s>>>(XZ, T1);
    gemm(s, 0, 1, XZ, T1, T2, LMM, LMM, LMM,
         (long)NH*sP, sP, LMM, (long)NH*sP, sP, LMM, (long)NH*sP, sP, LMM,
         BATCH*NH, NH, 1, 15.f, nullptr);
    gemm(s, 0, 1, XZ, T2, T1, LMM, LMM, LMM,
         (long)NH*sP, sP, LMM, (long)NH*sP, sP, LMM, (long)NH*sP, sP, LMM,
         BATCH*NH, NH, 1, 13.f, nullptr);
    gemm(s, 0, 2, Z, T1, XZ, LMM, LMM, LMM,
         (long)NH*sP, sP, LMM, (long)NH*sP, sP, LMM, (long)NH*sP, sP, LMM,
         BATCH*NH, NH, 1, 0.25f, nullptr);
    zi = oi[0];
  }
  float* Z = bufs[zi];
  int f1 = -1, f2 = -1;
  for (int i = 0; i < 4; ++i) if (i != zi) { if (f1 < 0) f1 = i; else if (f2 < 0) f2 = i; }
  float* t3  = bufs[f1];
  float* zt3 = bufs[f2];

  // ---- T3 = attn3 @ v (split-K atomic), then ZT3 = Z @ T3; a3 dead after ----
  zero_k<<<(unsigned)((SZ_L + TB - 1)/TB), TB, 0, s>>>(t3, SZ_L);
  gemm(s, 0, 4, a3, qkv + 2*CD, t3, LMM, DH, NP,
       (long)NH*LMM*NP, (long)LMM*NP, NP,  (long)NP*D3, 64, D3,  (long)NH*sL, sL, DH,
       BATCH*NH, NH, 8, 0.f, nullptr);
  gemm(s, 0, 0, Z, t3, zt3, LMM, DH, LMM,
       (long)NH*sP, sP, LMM,  (long)NH*sL, sL, DH,  (long)NH*sL, sL, DH,
       BATCH*NH, NH, 1, 0.f, nullptr);

  // ---- attn1 = softmax(SCALE * q @ kl^T) reusing a13 ----
  float* a1 = a13;
  gemm(s, 1, 2, qkv, kl, a1, NP, LMM, DH,
       (long)NP*D3, 64, D3,  (long)NH*sL, sL, DH,  (long)NH*NP*LMM, (long)NP*LMM, LMM,
       BATCH*NH, NH, 1, SCALE, nullptr);
  softmax256_k<<<BATCH*NH*NP, TB, 0, s>>>(a1);

  // ---- oh = attn1 @ zt3 (oh aliases x; ln output long consumed) ----
  float* oh = x;
  gemm(s, 0, 0, a1, zt3, oh, NP, DH, LMM,
       (long)NH*NP*LMM, (long)NP*LMM, LMM,  (long)NH*sL, sL, DH,
       (long)NH*NP*DH, (long)NP*DH, DH,
       BATCH*NH, NH, 1, 0.f, nullptr);

  addres_k<<<BATCH*NH*(NP/4), TB, 0, s>>>(qkv, res_w, oh);
  tr_k<<<BATCH*NP, TB, 0, s>>>(oh, a13);              // a1 dead; a13 = [b,i,c] staging
  gemm(s, 0, 3, a13, out_w, x, BATCH*NP, CD, CD,      // overwrites oh in place
       0, 0, CD,  0, 0, CD,  0, 0, CD,  1, 1, 1, 0.f, out_b);
  addh_k<<<(unsigned)((long)BATCH*NTOK*CD / TB), TB, 0, s>>>(x, h);
}

// ---------------- entry ----------------
extern "C" void kernel_launch(void* const* d_in, const int* in_sizes, int n_in,
                              void* d_out, int out_size, void* d_ws, size_t ws_size,
                              hipStream_t stream)
{
  if (ws_size < (size_t)WS_FLOATS * sizeof(float)) return;  // diagnostic guard

  const float* features = (const float*)d_in[0];
  const float* cls      = (const float*)d_in[1];
  const float* ln1_g = (const float*)d_in[2];
  const float* ln1_b = (const float*)d_in[3];
  const float* qkv1  = (const float*)d_in[4];
  const float* out1_w= (const float*)d_in[5];
  const float* out1_b= (const float*)d_in[6];
  const float* res1  = (const float*)d_in[7];
  const float* peg7_w= (const float*)d_in[8];
  const float* peg7_b= (const float*)d_in[9];
  const float* peg5_w= (const float*)d_in[10];
  const float* peg5_b= (const float*)d_in[11];
  const float* peg3_w= (const float*)d_in[12];
  const float* peg3_b= (const float*)d_in[13];
  const float* ln2_g = (const float*)d_in[14];
  const float* ln2_b = (const float*)d_in[15];
  const float* qkv2  = (const float*)d_in[16];
  const float* out2_w= (const float*)d_in[17];
  const float* out2_b= (const float*)d_in[18];
  const float* res2  = (const float*)d_in[19];
  const float* lnf_g = (const float*)d_in[20];
  const float* lnf_b = (const float*)d_in[21];
  float* ws  = (float*)d_ws;
  float* out = (float*)d_out;

  build_h_k<<<BATCH*NTOK, TB, 0, stream>>>(features, cls, ws + O_H);
  attention(ws, stream, ln1_g, ln1_b, qkv1, out1_w, out1_b, res1);
  ppeg_k<<<BATCH*NPIX, TB, 0, stream>>>(ws + O_H, peg7_w, peg7_b, peg5_w, peg5_b, peg3_w, peg3_b, ws + O_A13);
  ppeg_copy_k<<<BATCH*NPIX, TB, 0, stream>>>(ws + O_A13, ws + O_H);
  attention(ws, stream, ln2_g, ln2_b, qkv2, out2_w, out2_b, res2);
  ln_out_k<<<BATCH*NTOK, TB, 0, stream>>>(ws + O_H, lnf_g, lnf_b, out);
}

// Round 9
// 2877.755 us; speedup vs baseline: 1.4940x; 1.4940x over previous
//
// R9: resubmit of R7/R8 (broker timeouts; never ran). Experiment in flight: ppeg rewrite.
// R6 evidence: ppeg_k = 1600us/call (37% of 4299us) at VALUBusy 1.4%, HBM 1% ->
// latency-bound tap/neighbor thrash (FETCH 98MB/dispatch). Fix: fuse w7+w5+w3 into 49
// taps/ch, transpose to channel-planar, conv whole 78x78 plane from LDS, transpose back.
// Predicted: ppeg path ~1700us -> ~70us, total -> ~2700us. Rest identical to R6 (passed).
#include <hip/hip_runtime.h>

#define TB 256

constexpr int BATCH = 2;
constexpr int NF    = 6000;
constexpr int NTOK  = 6085;   // 1 cls + 6084
constexpr int NPIX  = 6084;   // 78*78
constexpr int HS    = 78;
constexpr int NP    = 6144;   // padded seq for landmarks
constexpr int PAD   = 59;     // front zero-pad
constexpr int CD    = 512;
constexpr int NH    = 8;
constexpr int DH    = 64;
constexpr int LMM   = 256;
constexpr int LSEG  = 24;     // NP / LMM
constexpr int D3    = 1536;
constexpr float SCALE = 0.125f;
constexpr int RESK  = 33;

// ---------------- workspace layout (floats) ----------------
constexpr long SZ_H   = (long)BATCH*NTOK*CD;     // 6,231,040
constexpr long SZ_X   = (long)BATCH*NP*CD;       // 6,291,456 (== SZ_OH, oh aliases x)
constexpr long SZ_QKV = (long)BATCH*NP*D3;       // 18,874,368
constexpr long SZ_L   = (long)BATCH*NH*LMM*DH;   // 262,144
constexpr long SZ_A13 = (long)BATCH*NH*NP*LMM;   // 25,165,824 (a3 then a1 then tr; ppeg planes)
constexpr long SZ_A2  = (long)BATCH*NH*LMM*LMM;  // 1,048,576
constexpr long SZ_P   = SZ_A2;                   // pinv ping-pong buffer
constexpr long SZ_PLANE = (long)BATCH*CD*NPIX;   // 6,230,016 (fits 2x inside A13)

constexpr long O_H   = 0;
constexpr long O_X   = O_H   + SZ_H;             // also OH
constexpr long O_QKV = O_X   + SZ_X;
constexpr long O_QL  = O_QKV + SZ_QKV;
constexpr long O_KL  = O_QL  + SZ_L;
constexpr long O_A13 = O_KL  + SZ_L;
constexpr long O_A2  = O_A13 + SZ_A13;
constexpr long O_P0  = O_A2  + SZ_A2;
constexpr long O_P1  = O_P0  + SZ_P;
constexpr long O_P2  = O_P1  + SZ_P;
constexpr long O_P3  = O_P2  + SZ_P;
constexpr long O_SCAL= O_P3  + SZ_P;
constexpr long WS_FLOATS = O_SCAL + 64;
// 62,329,920 floats = 237.8 MiB

// ---------------- reductions (blockDim == 256) ----------------
__device__ __forceinline__ float blkSum(float v, float* red) {
  #pragma unroll
  for (int o = 32; o > 0; o >>= 1) v += __shfl_xor(v, o);
  if ((threadIdx.x & 63) == 0) red[threadIdx.x >> 6] = v;
  __syncthreads();
  v = red[0] + red[1] + red[2] + red[3];
  __syncthreads();
  return v;
}
__device__ __forceinline__ float blkMax(float v, float* red) {
  #pragma unroll
  for (int o = 32; o > 0; o >>= 1) v = fmaxf(v, __shfl_xor(v, o));
  if ((threadIdx.x & 63) == 0) red[threadIdx.x >> 6] = v;
  __syncthreads();
  v = fmaxf(fmaxf(red[0], red[1]), fmaxf(red[2], red[3]));
  __syncthreads();
  return v;
}

// ---------------- generic tiled GEMM ----------------
// C[bh] = A[bh] @ B[bh]; BT: B given as (N x K) row-major (multiply by B^T)
// EP: 0 none | 1 c0*I - P | 2 c0*P | 3 P + bias[col] | 4 atomicAdd
template<int BT, int EP>
__global__ __launch_bounds__(256)
void gemm_k(const float* __restrict__ A, const float* __restrict__ Bp, float* __restrict__ Cp,
            int Ksz,
            long sAb, long sAh, int lda,
            long sBb, long sBh, int ldb,
            long sCb, long sCh, int ldc,
            int splitk, float c0, const float* __restrict__ bias, int Hdiv)
{
  constexpr int BM = 64, BN = 64, BK = 16;
  int z = blockIdx.z;
  int split = z % splitk;
  int bh = z / splitk;
  int bb = bh / Hdiv, hh = bh % Hdiv;
  const float* Ab = A  + bb*sAb + hh*sAh;
  const float* Bb = Bp + bb*sBb + hh*sBh;
  float*       Cb = Cp + bb*sCb + hh*sCh;
  int n0 = blockIdx.x * BN;
  int m0 = blockIdx.y * BM;
  int kPer = Ksz / splitk;
  int k0beg = split * kPer, k0end = k0beg + kPer;

  __shared__ float As[BK][BM + 4];
  __shared__ float Bs[BK][BN + 4];

  int tid = threadIdx.x;
  int tx = tid & 15, ty = tid >> 4;
  float acc[4][4] = {};

  for (int k0 = k0beg; k0 < k0end; k0 += BK) {
    {
      int m  = tid >> 2;
      int kk = (tid & 3) << 2;
      float4 v = *reinterpret_cast<const float4*>(Ab + (long)(m0 + m)*lda + k0 + kk);
      As[kk+0][m] = v.x; As[kk+1][m] = v.y; As[kk+2][m] = v.z; As[kk+3][m] = v.w;
    }
    if (BT == 0) {
      int kk = tid >> 4;
      int n4 = (tid & 15) << 2;
      float4 v = *reinterpret_cast<const float4*>(Bb + (long)(k0 + kk)*ldb + n0 + n4);
      *reinterpret_cast<float4*>(&Bs[kk][n4]) = v;
    } else {
      int n  = tid >> 2;
      int kk = (tid & 3) << 2;
      float4 v = *reinterpret_cast<const float4*>(Bb + (long)(n0 + n)*ldb + k0 + kk);
      Bs[kk+0][n] = v.x; Bs[kk+1][n] = v.y; Bs[kk+2][n] = v.z; Bs[kk+3][n] = v.w;
    }
    __syncthreads();
    #pragma unroll
    for (int kk = 0; kk < BK; ++kk) {
      float4 av = *reinterpret_cast<const float4*>(&As[kk][ty << 2]);
      float4 bv = *reinterpret_cast<const float4*>(&Bs[kk][tx << 2]);
      float a[4] = {av.x, av.y, av.z, av.w};
      float b[4] = {bv.x, bv.y, bv.z, bv.w};
      #pragma unroll
      for (int i = 0; i < 4; ++i)
        #pragma unroll
        for (int j = 0; j < 4; ++j)
          acc[i][j] += a[i] * b[j];
    }
    __syncthreads();
  }

  #pragma unroll
  for (int i = 0; i < 4; ++i) {
    int gm = m0 + (ty << 2) + i;
    long rowOff = (long)gm*ldc + n0 + (tx << 2);
    if (EP == 4) {
      #pragma unroll
      for (int j = 0; j < 4; ++j) atomicAdd(&Cb[rowOff + j], acc[i][j]);
    } else {
      float4 vv;
      float* pv = reinterpret_cast<float*>(&vv);
      #pragma unroll
      for (int j = 0; j < 4; ++j) {
        int gn = n0 + (tx << 2) + j;
        float r = acc[i][j];
        if (EP == 1) r = (gm == gn ? c0 : 0.f) - r;
        else if (EP == 2) r = c0 * r;
        else if (EP == 3) r = r + bias[gn];
        pv[j] = r;
      }
      *reinterpret_cast<float4*>(&Cb[rowOff]) = vv;
    }
  }
}

static void gemm(hipStream_t s, int BT, int EP,
                 const float* A, const float* Bp, float* Cp,
                 int Msz, int Nsz, int Ksz,
                 long sAb, long sAh, int lda,
                 long sBb, long sBh, int ldb,
                 long sCb, long sCh, int ldc,
                 int batch, int Hdiv, int splitk, float c0, const float* bias)
{
  dim3 g(Nsz/64, Msz/64, batch*splitk), t(256);
  #define GCALL(bt,ep) gemm_k<bt,ep><<<g,t,0,s>>>(A,Bp,Cp,Ksz,sAb,sAh,lda,sBb,sBh,ldb,sCb,sCh,ldc,splitk,c0,bias,Hdiv)
  if (BT == 0) {
    switch (EP) {
      case 0: GCALL(0,0); break; case 1: GCALL(0,1); break; case 2: GCALL(0,2); break;
      case 3: GCALL(0,3); break; case 4: GCALL(0,4); break;
    }
  } else {
    switch (EP) { case 0: GCALL(1,0); break; case 2: GCALL(1,2); break; }
  }
  #undef GCALL
}

// ---------------- misc kernels ----------------
__global__ __launch_bounds__(TB) void zero_k(float* __restrict__ p, long n) {
  long i = (long)blockIdx.x*TB + threadIdx.x;
  if (i < n) p[i] = 0.f;
}

__global__ __launch_bounds__(TB) void build_h_k(const float* __restrict__ f,
                                                const float* __restrict__ cls,
                                                float* __restrict__ h) {
  int r = blockIdx.x; int b = r / NTOK; int n = r % NTOK;
  const float* src;
  if (n == 0) src = cls;
  else { int rr = n - 1; if (rr >= NF) rr -= NF; src = f + ((long)b*NF + rr)*CD; }
  int t = threadIdx.x;
  h[(long)r*CD + t]       = src[t];
  h[(long)r*CD + t + 256] = src[t + 256];
}

__global__ __launch_bounds__(TB) void ln_pad_k(const float* __restrict__ h,
                                               const float* __restrict__ g,
                                               const float* __restrict__ be,
                                               float* __restrict__ x) {
  __shared__ float red[4];
  int r = blockIdx.x; int b = r / NP; int p = r % NP;
  float* o = x + (long)r*CD;
  int t = threadIdx.x;
  if (p < PAD) { o[t] = 0.f; o[t + 256] = 0.f; return; }
  const float* row = h + ((long)b*NTOK + (p - PAD))*CD;
  float v1 = row[t], v2 = row[t + 256];
  float mu = blkSum(v1 + v2, red) * (1.f/CD);
  float d1 = v1 - mu, d2 = v2 - mu;
  float var = blkSum(d1*d1 + d2*d2, red) * (1.f/CD);
  float inv = rsqrtf(var + 1e-5f);
  o[t]       = d1*inv*g[t]       + be[t];
  o[t + 256] = d2*inv*g[t + 256] + be[t + 256];
}

__global__ __launch_bounds__(TB) void ln_out_k(const float* __restrict__ h,
                                               const float* __restrict__ g,
                                               const float* __restrict__ be,
                                               float* __restrict__ out) {
  __shared__ float red[4];
  int r = blockIdx.x;
  const float* row = h + (long)r*CD;
  int t = threadIdx.x;
  float v1 = row[t], v2 = row[t + 256];
  float mu = blkSum(v1 + v2, red) * (1.f/CD);
  float d1 = v1 - mu, d2 = v2 - mu;
  float var = blkSum(d1*d1 + d2*d2, red) * (1.f/CD);
  float inv = rsqrtf(var + 1e-5f);
  out[(long)r*CD + t]       = d1*inv*g[t]       + be[t];
  out[(long)r*CD + t + 256] = d2*inv*g[t + 256] + be[t + 256];
}

__global__ __launch_bounds__(64) void landmark_k(const float* __restrict__ qkv,
                                                 float* __restrict__ ql,
                                                 float* __restrict__ kl) {
  int bid = blockIdx.x; int j = bid % LMM; int bh = bid / LMM;
  int b = bh / NH, h = bh % NH;
  int d = threadIdx.x;
  const float* qb = qkv + (long)b*NP*D3 + (long)j*LSEG*D3 + h*64 + d;
  float sq = 0.f, sk = 0.f;
  #pragma unroll 4
  for (int l = 0; l < LSEG; ++l) { sq += qb[(long)l*D3]; sk += qb[(long)l*D3 + CD]; }
  ql[((long)bh*LMM + j)*DH + d] = sq * (SCALE / LSEG);
  kl[((long)bh*LMM + j)*DH + d] = sk * (1.0f / LSEG);
}

__global__ __launch_bounds__(TB) void softmax256_k(float* __restrict__ a) {
  __shared__ float red[4];
  long row = blockIdx.x;
  float* p = a + row*256;
  float v = p[threadIdx.x];
  float m = blkMax(v, red);
  float e = __expf(v - m);
  float s = blkSum(e, red);
  p[threadIdx.x] = e / s;
}

__global__ __launch_bounds__(TB) void softmax_np_k(float* __restrict__ a) {
  __shared__ float buf[NP];
  __shared__ float red[4];
  long row = blockIdx.x;
  float* p = a + row*(long)NP;
  int t = threadIdx.x;
  float m = -1e30f;
  #pragma unroll
  for (int c = 0; c < NP/TB; ++c) { float v = p[c*TB + t]; buf[c*TB + t] = v; m = fmaxf(m, v); }
  m = blkMax(m, red);
  float s = 0.f;
  #pragma unroll
  for (int c = 0; c < NP/TB; ++c) { float e = __expf(buf[c*TB + t] - m); buf[c*TB + t] = e; s += e; }
  s = blkSum(s, red);
  float inv = 1.f / s;
  #pragma unroll
  for (int c = 0; c < NP/TB; ++c) p[c*TB + t] = buf[c*TB + t] * inv;
}

__global__ void scal_init_k(float* scal) { if (threadIdx.x < 8) scal[threadIdx.x] = 0.f; }

__global__ __launch_bounds__(TB) void pinv_prep_k(const float* __restrict__ a2, float* scal) {
  __shared__ float red[4];
  int bh = blockIdx.x;
  const float* X = a2 + (long)bh*LMM*LMM;
  int t = threadIdx.x;
  float cs = 0.f, rs = 0.f;
  for (int i = 0; i < LMM; ++i) cs += X[(long)i*LMM + t];
  for (int j = 0; j < LMM; ++j) rs += X[(long)t*LMM + j];
  float mc = blkMax(cs, red);
  float mr = blkMax(rs, red);
  if (t == 0) {
    atomicMax((unsigned int*)&scal[0], __float_as_uint(mr));
    atomicMax((unsigned int*)&scal[1], __float_as_uint(mc));
  }
}

__global__ __launch_bounds__(TB) void z0_k(const float* __restrict__ a2,
                                           const float* __restrict__ scal,
                                           float* __restrict__ z) {
  int i = blockIdx.x; int bh = blockIdx.y; int j = threadIdx.x;
  float inv = 1.f / (scal[0] * scal[1]);
  z[((long)bh*LMM + i)*LMM + j] = a2[((long)bh*LMM + j)*LMM + i] * inv;
}

__global__ __launch_bounds__(TB) void t7_k(const float* __restrict__ xz, float* __restrict__ t1) {
  int i = blockIdx.x; int bh = blockIdx.y; int j = threadIdx.x;
  long off = ((long)bh*LMM + i)*LMM + j;
  t1[off] = (i == j ? 7.f : 0.f) - xz[off];
}

__global__ __launch_bounds__(TB) void addres_k(const float* __restrict__ qkv,
                                               const float* __restrict__ rw,
                                               float* __restrict__ oh) {
  int bid = blockIdx.x;
  int i4 = bid % (NP/4); int bh = bid / (NP/4);
  int b = bh / NH, h = bh % NH;
  int i = i4*4 + (threadIdx.x >> 6);
  int d = threadIdx.x & 63;
  const float* vb = qkv + (long)b*NP*D3 + 2*CD + h*64 + d;
  float s = 0.f;
  #pragma unroll
  for (int t = 0; t < RESK; ++t) {
    int j = i + t - RESK/2;
    if (j >= 0 && j < NP) s += rw[h*RESK + t] * vb[(long)j*D3];
  }
  oh[((long)bh*NP + i)*DH + d] += s;
}

__global__ __launch_bounds__(TB) void tr_k(const float* __restrict__ oh, float* __restrict__ tr) {
  int r = blockIdx.x; int b = r / NP; int i = r % NP;
  #pragma unroll
  for (int cc = 0; cc < 2; ++cc) {
    int c = threadIdx.x + cc*256;
    int hh = c >> 6, d = c & 63;
    tr[(long)r*CD + c] = oh[(((long)b*NH + hh)*NP + i)*DH + d];
  }
}

__global__ __launch_bounds__(TB) void addh_k(const float* __restrict__ ao, float* __restrict__ h) {
  long idx = (long)blockIdx.x*TB + threadIdx.x;
  long b = idx / ((long)NTOK*CD);
  long rem = idx - b*(long)NTOK*CD;
  h[idx] += ao[b*(long)NP*CD + (long)PAD*CD + rem];
}

// ---------------- PPEG (channel-planar) ----------------
// Fuse w7 + center-padded w5 + center-padded w3 into one 7x7 tap set per channel.
__global__ __launch_bounds__(64) void fuse_w_k(const float* __restrict__ w7, const float* __restrict__ b7,
                                               const float* __restrict__ w5, const float* __restrict__ b5,
                                               const float* __restrict__ w3, const float* __restrict__ b3,
                                               float* __restrict__ wf, float* __restrict__ bf) {
  int c = blockIdx.x;
  int t = threadIdx.x;
  if (t < 49) {
    int dy = t / 7, dx = t % 7;
    float w = w7[(long)c*49 + t];
    if (dy >= 1 && dy <= 5 && dx >= 1 && dx <= 5) w += w5[(long)c*25 + (dy-1)*5 + (dx-1)];
    if (dy >= 2 && dy <= 4 && dx >= 2 && dx <= 4) w += w3[(long)c*9  + (dy-2)*3 + (dx-2)];
    wf[(long)c*49 + t] = w;
  }
  if (t == 0) bf[c] = b7[c] + b5[c] + b3[c];
}

// hp[b][c][n] = h[b][1+n][c]  (32x32 LDS tile transpose)
__global__ __launch_bounds__(TB) void tr_fwd_k(const float* __restrict__ h, float* __restrict__ hp) {
  __shared__ float t[32][33];
  int n0 = blockIdx.x * 32, c0 = blockIdx.y * 32, b = blockIdx.z;
  int tx = threadIdx.x & 31, ty = threadIdx.x >> 5;   // 32 x 8
  #pragma unroll
  for (int i = 0; i < 4; ++i) {
    int row = ty + i*8;
    int n = n0 + row;
    if (n < NPIX) t[row][tx] = h[((long)b*NTOK + 1 + n)*CD + c0 + tx];
  }
  __syncthreads();
  #pragma unroll
  for (int i = 0; i < 4; ++i) {
    int row = ty + i*8;          // channel offset
    int n = n0 + tx;
    if (n < NPIX) hp[((long)b*CD + c0 + row)*NPIX + n] = t[tx][row];
  }
}

// One block per (b,c): whole 78x78 plane + 49 taps in LDS.
__global__ __launch_bounds__(TB) void conv_plane_k(const float* __restrict__ hp,
                                                   const float* __restrict__ wf,
                                                   const float* __restrict__ bf,
                                                   float* __restrict__ tp) {
  __shared__ float plane[NPIX];
  __shared__ float w[50];
  int bc = blockIdx.x;            // b*CD + c
  int c = bc % CD;
  const float* src = hp + (long)bc*NPIX;
  int tid = threadIdx.x;
  for (int n = tid; n < NPIX; n += TB) plane[n] = src[n];
  if (tid < 49) w[tid] = wf[(long)c*49 + tid];
  if (tid == 49) w[49] = bf[c];
  __syncthreads();
  float* dst = tp + (long)bc*NPIX;
  for (int n = tid; n < NPIX; n += TB) {
    int y = n / HS, x = n - y*HS;
    float acc = plane[n] + w[49];
    #pragma unroll
    for (int dy = 0; dy < 7; ++dy) {
      int yy = y + dy - 3;
      if (yy < 0 || yy >= HS) continue;
      int base = yy * HS;
      #pragma unroll
      for (int dx = 0; dx < 7; ++dx) {
        int xx = x + dx - 3;
        if (xx >= 0 && xx < HS) acc += w[dy*7+dx] * plane[base + xx];
      }
    }
    dst[n] = acc;
  }
}

// h[b][1+n][c] = tp[b][c][n]  (inverse tile transpose; row 0 / cls untouched)
__global__ __launch_bounds__(TB) void tr_bwd_k(const float* __restrict__ tp, float* __restrict__ h) {
  __shared__ float t[32][33];
  int n0 = blockIdx.x * 32, c0 = blockIdx.y * 32, b = blockIdx.z;
  int tx = threadIdx.x & 31, ty = threadIdx.x >> 5;
  #pragma unroll
  for (int i = 0; i < 4; ++i) {
    int row = ty + i*8;          // channel offset
    int n = n0 + tx;
    if (n < NPIX) t[row][tx] = tp[((long)b*CD + c0 + row)*NPIX + n];
  }
  __syncthreads();
  #pragma unroll
  for (int i = 0; i < 4; ++i) {
    int row = ty + i*8;          // pixel offset
    int n = n0 + row;
    if (n < NPIX) h[((long)b*NTOK + 1 + n)*CD + c0 + tx] = t[tx][row];
  }
}

// ---------------- attention block ----------------
static void attention(float* ws, hipStream_t s,
                      const float* ln_g, const float* ln_b,
                      const float* qkv_w, const float* out_w, const float* out_b,
                      const float* res_w)
{
  float* h   = ws + O_H;
  float* x   = ws + O_X;     // ln output; later reused as oh and as out-proj dest
  float* qkv = ws + O_QKV;
  float* ql  = ws + O_QL;  float* kl = ws + O_KL;
  float* a13 = ws + O_A13;   // a3, then a1, then tr staging
  float* a2  = ws + O_A2;
  float* scal= ws + O_SCAL;
  float* bufs[4] = {ws + O_P0, ws + O_P1, ws + O_P2, ws + O_P3};

  const long sP = (long)LMM*LMM;
  const long sL = (long)LMM*DH;

  ln_pad_k<<<BATCH*NP, TB, 0, s>>>(h, ln_g, ln_b, x);
  gemm(s, 0, 0, x, qkv_w, qkv, BATCH*NP, D3, CD,
       0, 0, CD,  0, 0, D3,  0, 0, D3,  1, 1, 1, 0.f, nullptr);
  landmark_k<<<BATCH*NH*LMM, 64, 0, s>>>(qkv, ql, kl);

  // ---- attn3 = softmax(ql @ k^T) into a13 (first use) ----
  float* a3 = a13;
  gemm(s, 1, 0, ql, qkv + CD, a3, LMM, NP, DH,
       (long)NH*sL, sL, DH,  (long)NP*D3, 64, D3,  (long)NH*LMM*NP, (long)LMM*NP, NP,
       BATCH*NH, NH, 1, 0.f, nullptr);
  softmax_np_k<<<BATCH*NH*LMM, TB, 0, s>>>(a3);

  // ---- attn2 = softmax(ql @ kl^T) ----
  gemm(s, 1, 0, ql, kl, a2, LMM, LMM, DH,
       (long)NH*sL, sL, DH,  (long)NH*sL, sL, DH,  (long)NH*sP, sP, LMM,
       BATCH*NH, NH, 1, 0.f, nullptr);
  softmax256_k<<<BATCH*NH*LMM, TB, 0, s>>>(a2);

  // ---- pinv(attn2) ----
  scal_init_k<<<1, 64, 0, s>>>(scal);
  pinv_prep_k<<<BATCH*NH, TB, 0, s>>>(a2, scal);
  int zi = 0;
  z0_k<<<dim3(LMM, BATCH*NH), TB, 0, s>>>(a2, scal, bufs[zi]);
  for (int it = 0; it < 6; ++it) {
    int oi[3], c = 0;
    for (int i = 0; i < 4; ++i) if (i != zi) oi[c++] = i;
    float* Z  = bufs[zi];
    float* XZ = bufs[oi[0]]; float* T1 = bufs[oi[1]]; float* T2 = bufs[oi[2]];
    gemm(s, 0, 0, a2, Z, XZ, LMM, LMM, LMM,
         (long)NH*sP, sP, LMM, (long)NH*sP, sP, LMM, (long)NH*sP, sP, LMM,
         BATCH*NH, NH, 1, 0.f, nullptr);
    t7_k<<<dim3(LMM, BATCH*NH), TB, 0, s>>>(XZ, T1);
    gemm(s, 0, 1, XZ, T1, T2, LMM, LMM, LMM,
         (long)NH*sP, sP, LMM, (long)NH*sP, sP, LMM, (long)NH*sP, sP, LMM,
         BATCH*NH, NH, 1, 15.f, nullptr);
    gemm(s, 0, 1, XZ, T2, T1, LMM, LMM, LMM,
         (long)NH*sP, sP, LMM, (long)NH*sP, sP, LMM, (long)NH*sP, sP, LMM,
         BATCH*NH, NH, 1, 13.f, nullptr);
    gemm(s, 0, 2, Z, T1, XZ, LMM, LMM, LMM,
         (long)NH*sP, sP, LMM, (long)NH*sP, sP, LMM, (long)NH*sP, sP, LMM,
         BATCH*NH, NH, 1, 0.25f, nullptr);
    zi = oi[0];
  }
  float* Z = bufs[zi];
  int f1 = -1, f2 = -1;
  for (int i = 0; i < 4; ++i) if (i != zi) { if (f1 < 0) f1 = i; else if (f2 < 0) f2 = i; }
  float* t3  = bufs[f1];
  float* zt3 = bufs[f2];

  // ---- T3 = attn3 @ v (split-K atomic), then ZT3 = Z @ T3; a3 dead after ----
  zero_k<<<(unsigned)((SZ_L + TB - 1)/TB), TB, 0, s>>>(t3, SZ_L);
  gemm(s, 0, 4, a3, qkv + 2*CD, t3, LMM, DH, NP,
       (long)NH*LMM*NP, (long)LMM*NP, NP,  (long)NP*D3, 64, D3,  (long)NH*sL, sL, DH,
       BATCH*NH, NH, 8, 0.f, nullptr);
  gemm(s, 0, 0, Z, t3, zt3, LMM, DH, LMM,
       (long)NH*sP, sP, LMM,  (long)NH*sL, sL, DH,  (long)NH*sL, sL, DH,
       BATCH*NH, NH, 1, 0.f, nullptr);

  // ---- attn1 = softmax(SCALE * q @ kl^T) reusing a13 ----
  float* a1 = a13;
  gemm(s, 1, 2, qkv, kl, a1, NP, LMM, DH,
       (long)NP*D3, 64, D3,  (long)NH*sL, sL, DH,  (long)NH*NP*LMM, (long)NP*LMM, LMM,
       BATCH*NH, NH, 1, SCALE, nullptr);
  softmax256_k<<<BATCH*NH*NP, TB, 0, s>>>(a1);

  // ---- oh = attn1 @ zt3 (oh aliases x; ln output long consumed) ----
  float* oh = x;
  gemm(s, 0, 0, a1, zt3, oh, NP, DH, LMM,
       (long)NH*NP*LMM, (long)NP*LMM, LMM,  (long)NH*sL, sL, DH,
       (long)NH*NP*DH, (long)NP*DH, DH,
       BATCH*NH, NH, 1, 0.f, nullptr);

  addres_k<<<BATCH*NH*(NP/4), TB, 0, s>>>(qkv, res_w, oh);
  tr_k<<<BATCH*NP, TB, 0, s>>>(oh, a13);              // a1 dead; a13 = [b,i,c] staging
  gemm(s, 0, 3, a13, out_w, x, BATCH*NP, CD, CD,      // overwrites oh in place
       0, 0, CD,  0, 0, CD,  0, 0, CD,  1, 1, 1, 0.f, out_b);
  addh_k<<<(unsigned)((long)BATCH*NTOK*CD / TB), TB, 0, s>>>(x, h);
}

// ---------------- entry ----------------
extern "C" void kernel_launch(void* const* d_in, const int* in_sizes, int n_in,
                              void* d_out, int out_size, void* d_ws, size_t ws_size,
                              hipStream_t stream)
{
  if (ws_size < (size_t)WS_FLOATS * sizeof(float)) return;  // diagnostic guard

  const float* features = (const float*)d_in[0];
  const float* cls      = (const float*)d_in[1];
  const float* ln1_g = (const float*)d_in[2];
  const float* ln1_b = (const float*)d_in[3];
  const float* qkv1  = (const float*)d_in[4];
  const float* out1_w= (const float*)d_in[5];
  const float* out1_b= (const float*)d_in[6];
  const float* res1  = (const float*)d_in[7];
  const float* peg7_w= (const float*)d_in[8];
  const float* peg7_b= (const float*)d_in[9];
  const float* peg5_w= (const float*)d_in[10];
  const float* peg5_b= (const float*)d_in[11];
  const float* peg3_w= (const float*)d_in[12];
  const float* peg3_b= (const float*)d_in[13];
  const float* ln2_g = (const float*)d_in[14];
  const float* ln2_b = (const float*)d_in[15];
  const float* qkv2  = (const float*)d_in[16];
  const float* out2_w= (const float*)d_in[17];
  const float* out2_b= (const float*)d_in[18];
  const float* res2  = (const float*)d_in[19];
  const float* lnf_g = (const float*)d_in[20];
  const float* lnf_b = (const float*)d_in[21];
  float* ws  = (float*)d_ws;
  float* out = (float*)d_out;

  build_h_k<<<BATCH*NTOK, TB, 0, stream>>>(features, cls, ws + O_H);
  attention(ws, stream, ln1_g, ln1_b, qkv1, out1_w, out1_b, res1);

  // ---- PPEG: fuse weights, transpose to planar, LDS conv, transpose back ----
  {
    float* hp  = ws + O_A13;                 // [B][C][NPIX]
    float* tp  = ws + O_A13 + SZ_PLANE;      // [B][C][NPIX]
    float* wf  = ws + O_P0;                  // [C][49]
    float* bf  = ws + O_P0 + (long)CD*49;    // [C]
    fuse_w_k<<<CD, 64, 0, stream>>>(peg7_w, peg7_b, peg5_w, peg5_b, peg3_w, peg3_b, wf, bf);
    dim3 tg((NPIX + 31)/32, CD/32, BATCH);
    tr_fwd_k<<<tg, TB, 0, stream>>>(ws + O_H, hp);
    conv_plane_k<<<BATCH*CD, TB, 0, stream>>>(hp, wf, bf, tp);
    tr_bwd_k<<<tg, TB, 0, stream>>>(tp, ws + O_H);
  }

  attention(ws, stream, ln2_g, ln2_b, qkv2, out2_w, out2_b, res2);
  ln_out_k<<<BATCH*NTOK, TB, 0, stream>>>(ws + O_H, lnf_g, lnf_b, out);
}